// Round 7
// baseline (310.451 us; speedup 1.0000x reference)
//
#include <hip/hip_runtime.h>
#include <math.h>

// Quantized causal attention on int8 MFMA — R7.
// R6 post-mortem: main 129->142us. P2 direct-global K-frag loads exposed L2
// latency (load -> immediate MFMA after barrier). Both util counters fell.
// R7:
//  1. k8s/v8s union (k8s is P1-only now) -> LDS 61440->43008 -> 3 blocks/CU
//     (__launch_bounds__(256,3); 12 waves/CU for latency hiding).
//  2. Cross-tile REGISTER prefetch done right (R5 spilled via conditionally-
//     initialized arrays): scalar named uint4 regs, UNCONDITIONAL loads with
//     clamped next-index. P1: next K-tile + consts load right after staging
//     barrier (whole tile compute to land). P2: next V-tile + consts same;
//     K-fragments reloaded right after their use (PV covers them).

#define S_LEN 2048
#define BATCH 2
#define NH    16
#define HD    128
#define RSTR  4096   // floats between seq positions
#define SCALE2 (0.08838834764831845f * 1.4426950408889634f)   // (1/sqrt(128))/ln2
#define EXP2F(x) __builtin_amdgcn_exp2f(x)

typedef int v4i __attribute__((ext_vector_type(4)));
#define MFMA16(a,b,c) __builtin_amdgcn_mfma_i32_16x16x64_i8((a),(b),(c),0,0,0)

// ws byte offsets (total ~16.8 MB)
#define WS_K8   0u
#define WS_V8T  (8u*1024u*1024u)
#define WS_SQ   (16u*1024u*1024u)
#define WS_SK   (WS_SQ + 256u*1024u)
#define WS_GSV  (WS_SK + 256u*1024u)

__device__ __forceinline__ int sbsum(unsigned p) {
    return (int)(signed char)(p) + (int)(signed char)(p>>8)
         + (int)(signed char)(p>>16) + (int)(signed char)(p>>24);
}

// ---- fused pre-kernel: Q/K token sums + K int8 pack  |  V transpose + GSV ----
__global__ __launch_bounds__(256) void prep_pack(
    const float* __restrict__ Q, const float* __restrict__ K, const float* __restrict__ V,
    signed char* __restrict__ K8, float* __restrict__ SQs, float* __restrict__ SKs,
    signed char* __restrict__ V8T, float* __restrict__ GSV)
{
    __shared__ int v8i[128*33];
    const int tid = threadIdx.x;
    const int bx  = blockIdx.x;
    if (bx < 16384) {
        const int tensor = bx >> 13;
        const int idx = (bx & 8191)*256 + tid;
        const float* src = tensor ? K : Q;
        int tau = idx >> 5, dg = idx & 31;
        float4 x = *(const float4*)(src + (size_t)tau*128 + 4*dg);
        float ssum = x.x + x.y + x.z + x.w;
        #pragma unroll
        for (int off = 16; off >= 1; off >>= 1) ssum += __shfl_xor(ssum, off);
        if (tensor) {
            int a=(int)x.x, b2=(int)x.y, c=(int)x.z, d=(int)x.w;
            ((int*)K8)[(size_t)tau*32 + dg] = (a&255)|((b2&255)<<8)|((c&255)<<16)|((d&255)<<24);
            if ((tid & 31) == 0) SKs[tau] = ssum;
        } else {
            if ((tid & 31) == 0) SQs[tau] = ssum;
        }
    } else {
        const int bid = bx - 16384;
        const int bh = bid & 31, ck = bid >> 5;   // ck = 128-t chunk = v-group
        const int b = bh >> 4, h = bh & 15;
        const int t0 = ck * 128;
        const int boff = b*2048 + h*128;
        #pragma unroll
        for (int it = 0; it < 16; ++it) {
            int idx = tid + it*256;
            int t = idx >> 5, dw = idx & 31;
            float4 x = *(const float4*)(V + (size_t)(t0+t)*RSTR + boff + 4*dw);
            int a=(int)x.x, b2=(int)x.y, c=(int)x.z, d=(int)x.w;
            v8i[t*33 + dw] = (a&255)|((b2&255)<<8)|((c&255)<<16)|((d&255)<<24);
        }
        __syncthreads();
        #pragma unroll
        for (int it = 0; it < 4; ++it) {
            int j = tid + it*256;
            int tg = j & 31, dw = j >> 5;
            unsigned r0 = (unsigned)v8i[(4*tg+0)*33 + dw];
            unsigned r1 = (unsigned)v8i[(4*tg+1)*33 + dw];
            unsigned r2 = (unsigned)v8i[(4*tg+2)*33 + dw];
            unsigned r3 = (unsigned)v8i[(4*tg+3)*33 + dw];
            unsigned x01 = __builtin_amdgcn_perm(r1, r0, 0x05010400u);
            unsigned x23 = __builtin_amdgcn_perm(r3, r2, 0x05010400u);
            unsigned y01 = __builtin_amdgcn_perm(r1, r0, 0x07030602u);
            unsigned y23 = __builtin_amdgcn_perm(r3, r2, 0x07030602u);
            unsigned p[4];
            p[0] = __builtin_amdgcn_perm(x23, x01, 0x05040100u);
            p[1] = __builtin_amdgcn_perm(x23, x01, 0x07060302u);
            p[2] = __builtin_amdgcn_perm(y23, y01, 0x05040100u);
            p[3] = __builtin_amdgcn_perm(y23, y01, 0x07060302u);
            int s[4];
            #pragma unroll
            for (int jj = 0; jj < 4; ++jj) {
                int d = 4*dw + jj;
                *(int*)(V8T + ((size_t)bh*128 + d)*2048 + t0 + 4*tg) = (int)p[jj];
                s[jj] = sbsum(p[jj]);
            }
            #pragma unroll
            for (int off = 1; off < 32; off <<= 1) {
                #pragma unroll
                for (int jj = 0; jj < 4; ++jj) s[jj] += __shfl_xor(s[jj], off);
            }
            if (tg == 0) {
                #pragma unroll
                for (int jj = 0; jj < 4; ++jj)
                    GSV[((size_t)bh*16 + ck)*128 + 4*dw + jj] = (float)s[jj];
            }
        }
    }
}

// ---- main kernel ----
__global__ __launch_bounds__(256, 3) void attn_main(
    const float* __restrict__ Q,
    const signed char* __restrict__ K8, const signed char* __restrict__ V8T,
    const float* __restrict__ QMN, const float* __restrict__ QSC,
    const float* __restrict__ KMN, const float* __restrict__ KSC,
    const float* __restrict__ VMN, const float* __restrict__ VSC,
    const float* __restrict__ SQs, const float* __restrict__ SKs,
    const float* __restrict__ GSV,
    const int* __restrict__ CAUSAL, float* __restrict__ OUT)
{
    __shared__ __align__(16) signed char q8s[64*144];    // [q][d] int8
    __shared__ __align__(16) signed char kv8s[128*144];  // P1: K[t][d]; P2: V[d][t]
    __shared__ __align__(16) signed char pcs[64*144];    // [q][t] code' int8
    __shared__ float rs_c1[64], rs_c2[64], rs_c3[64];
    __shared__ float rs_mx[64], rs_den[64], rs_mn[64];
    __shared__ float rs_u1[64], rs_w1[64], rs_psc[64], rs_pmn[64];
    __shared__ float ktA[128], ktB[128], ktC[128];       // ks*S2, km*S2, sk8
    __shared__ float vsA[128], vsB[128];                 // vs, vm (current group)
    __shared__ float vsumL[128], cgsL[128];              // in-block VSUM / CGS row

    const int tid  = threadIdx.x;
    const int w    = tid >> 6;
    const int lane = tid & 63;
    const int n    = lane & 15;
    const int quad = lane >> 4;
    const int bhi  = blockIdx.x & 31;
    const int qt   = 31 - (int)(blockIdx.x >> 5);   // heavy tiles first
    const int b    = bhi >> 4, h = bhi & 15;
    const int causal = *CAUSAL;
    const int s0   = qt * 64;
    const int boff = b*2048 + h*128;
    const int trb  = tid >> 3;          // staging row base (0..31)
    const int tdo  = (tid & 7) << 4;    // staging byte offset (0..112)
    const int tc   = tid & 127;         // const-lane index
    const v4i vzero = {0,0,0,0};
    const v4i ones  = {0x01010101,0x01010101,0x01010101,0x01010101};

    // ---- stage Q tile (float -> int8 LDS) + per-row consts ----
    #pragma unroll
    for (int it = 0; it < 8; ++it) {
        int idx = tid + it*256;
        int row = idx >> 5, d4 = (idx & 31) << 2;
        float4 x = *(const float4*)(Q + (size_t)(s0+row)*RSTR + boff + d4);
        int a=(int)x.x, b2=(int)x.y, c=(int)x.z, d=(int)x.w;
        *(int*)(q8s + row*144 + d4) = (a&255)|((b2&255)<<8)|((c&255)<<16)|((d&255)<<24);
    }
    if (tid < 64) {
        int si = (s0 + tid)*32 + bhi;
        float qs = QSC[si], qm = QMN[si];
        rs_c1[tid] = qs; rs_c2[tid] = qm;
        rs_c3[tid] = fmaf(qs, SQs[si], 128.0f*qm);
    }
    __syncthreads();

    const int kt_end = causal ? ((s0 + 63) >> 7) : 15;

    float c1r[4], c2r[4], c3r[4]; int qgr[4];
    #pragma unroll
    for (int r = 0; r < 4; ++r) {
        int qq = 16*w + 4*quad + r;
        c1r[r] = rs_c1[qq]; c2r[r] = rs_c2[qq]; c3r[r] = rs_c3[qq];
        qgr[r] = s0 + qq;
    }
    v4i a0p = *(const v4i*)(q8s + (16*w + n)*144 + 16*quad);
    v4i a1p = *(const v4i*)(q8s + (16*w + n)*144 + 64 + 16*quad);

    float m[4], l[4], mn[4];
    #pragma unroll
    for (int r = 0; r < 4; ++r) { m[r] = -INFINITY; l[r] = 0.f; mn[r] = INFINITY; }

#define KSTG(KT,IT) (const uint4*)(K8 + ((size_t)((KT)*128 + trb + 32*(IT))*32 + bhi)*128 + tdo)
#define VSTG(KT,IT) (const uint4*)(V8T + ((size_t)bhi*128 + trb + 32*(IT))*2048 + (KT)*128 + tdo)

#define P1_COMPUTE(MASKED, T0G)                                                  \
  do {                                                                           \
    float tmax[4], sarr[8][4];                                                   \
    _Pragma("unroll")                                                            \
    for (int r = 0; r < 4; ++r) tmax[r] = -INFINITY;                             \
    _Pragma("unroll")                                                            \
    for (int tb = 0; tb < 8; ++tb) {                                             \
        v4i b0 = *(const v4i*)(kv8s + (16*tb + n)*144 + 16*quad);                \
        v4i b1 = *(const v4i*)(kv8s + (16*tb + n)*144 + 64 + 16*quad);           \
        v4i acc = MFMA16(a0p, b0, vzero);                                        \
        acc = MFMA16(a1p, b1, acc);                                              \
        int tl = 16*tb + n;                                                      \
        float kA = ktA[tl], kB = ktB[tl], kC = ktC[tl];                          \
        _Pragma("unroll")                                                        \
        for (int r = 0; r < 4; ++r) {                                            \
            float Sf = (float)acc[r];                                            \
            float sv = fmaf(kA, fmaf(c1r[r], Sf, c2r[r]*kC), kB*c3r[r]);         \
            if (MASKED) sv = ((T0G) + tl > qgr[r]) ? -INFINITY : sv;             \
            sarr[tb][r] = sv;                                                    \
            tmax[r] = fmaxf(tmax[r], sv);                                        \
            mn[r] = fminf(mn[r], sv);                                            \
        }                                                                        \
    }                                                                            \
    _Pragma("unroll")                                                            \
    for (int r = 0; r < 4; ++r) {                                                \
        float mm = fmaxf(m[r], tmax[r]);                                         \
        if (mm > -INFINITY) {                                                    \
            float e0 = EXP2F(sarr[0][r]-mm) + EXP2F(sarr[1][r]-mm);              \
            float e1 = EXP2F(sarr[2][r]-mm) + EXP2F(sarr[3][r]-mm);              \
            float e2 = EXP2F(sarr[4][r]-mm) + EXP2F(sarr[5][r]-mm);              \
            float e3 = EXP2F(sarr[6][r]-mm) + EXP2F(sarr[7][r]-mm);              \
            l[r] = fmaf(l[r], EXP2F(m[r]-mm), (e0+e1)+(e2+e3));                  \
            m[r] = mm;                                                           \
        }                                                                        \
    }                                                                            \
  } while (0)

    // ================= Phase 1 (register-prefetched staging) =================
    {
        uint4 pk0 = *KSTG(0,0), pk1 = *KSTG(0,1), pk2 = *KSTG(0,2), pk3 = *KSTG(0,3);
        int si0 = tc*32 + bhi;
        float nA = KSC[si0], nB = KMN[si0], nC = SKs[si0];
        for (int kt = 0; ; ++kt) {
            __syncthreads();                 // prior compute's kv8s reads done
            *(uint4*)(kv8s + (trb+ 0)*144 + tdo) = pk0;
            *(uint4*)(kv8s + (trb+32)*144 + tdo) = pk1;
            *(uint4*)(kv8s + (trb+64)*144 + tdo) = pk2;
            *(uint4*)(kv8s + (trb+96)*144 + tdo) = pk3;
            if (tid < 128) { ktA[tid] = nA*SCALE2; ktB[tid] = nB*SCALE2; ktC[tid] = nC; }
            __syncthreads();
            const int kn = (kt < kt_end) ? kt + 1 : kt_end;   // clamped next
            pk0 = *KSTG(kn,0); pk1 = *KSTG(kn,1); pk2 = *KSTG(kn,2); pk3 = *KSTG(kn,3);
            { int si = (kn*128 + tc)*32 + bhi; nA = KSC[si]; nB = KMN[si]; nC = SKs[si]; }
            if (causal && kt == kt_end) P1_COMPUTE(true, kt*128);
            else                        P1_COMPUTE(false, kt*128);
            if (kt == kt_end) break;
        }
    }

    // reduce stats across the 16 col-lanes
    #pragma unroll
    for (int r = 0; r < 4; ++r) {
        #pragma unroll
        for (int off = 1; off < 16; off <<= 1) {
            float m2 = __shfl_xor(m[r], off);
            float l2 = __shfl_xor(l[r], off);
            float n2 = __shfl_xor(mn[r], off);
            float mm = fmaxf(m[r], m2);
            if (mm > -INFINITY) l[r] = l[r]*EXP2F(m[r]-mm) + l2*EXP2F(m2-mm);
            m[r] = mm;
            mn[r] = fminf(mn[r], n2);
        }
        if (n == 0) {
            int qq = 16*w + 4*quad + r;
            rs_mx[qq] = m[r]; rs_den[qq] = l[r]; rs_mn[qq] = mn[r];
        }
    }
    __syncthreads();
    if (tid < 64) {
        float mx = rs_mx[tid], den = rs_den[tid], mnv = rs_mn[tid];
        float invd = 1.0f/den;
        int s = s0 + tid;
        bool hasmask = (causal != 0) && (s < S_LEN-1);
        float pmin = hasmask ? 0.0f : EXP2F(mnv - mx)*invd;
        float psc  = (invd - pmin)/255.0f + 1e-12f;
        float ipsc = 1.0f/psc;
        rs_u1[tid] = invd*ipsc; rs_w1[tid] = -pmin*ipsc;
        rs_psc[tid] = psc; rs_pmn[tid] = pmin;
    } else if (tid >= 128) {
        // in-block VSUM (full row) + CGS (cumulative to kt_end) for this bh
        int d = tid - 128;
        float vsum = 0.f, cgs = 0.f;
        #pragma unroll
        for (int g = 0; g < 16; ++g) {
            float gs = GSV[((size_t)bhi*16 + g)*128 + d];
            int vi = ((g*BATCH + b)*NH + h)*HD + d;
            float vs = VSC[vi], vm = VMN[vi];
            vsum = fmaf(vs, gs, fmaf(128.0f, vm, vsum));
            if (g <= kt_end) cgs = fmaf(128.0f*vs, gs, fmaf(16384.0f, vm, cgs));
        }
        vsumL[d] = vsum; cgsL[d] = cgs;
    }
    __syncthreads();

    // ---- hoist P2 tile-invariants: Q B-fragments + per-q constants ----
    v4i qb0[4], qb1[4];
    float qc1[4], qc2[4], qc3[4], qmxn[4], qu1[4], qw1[4];
    int qgq[4];
    #pragma unroll
    for (int cb = 0; cb < 4; ++cb) {
        int qcol = 16*cb + n;
        qb0[cb] = *(const v4i*)(q8s + qcol*144 + 16*quad);
        qb1[cb] = *(const v4i*)(q8s + qcol*144 + 64 + 16*quad);
        qc1[cb] = rs_c1[qcol]; qc2[cb] = rs_c2[qcol]; qc3[cb] = rs_c3[qcol];
        qmxn[cb] = -rs_mx[qcol]; qu1[cb] = rs_u1[qcol]; qw1[cb] = rs_w1[qcol];
        qgq[cb] = s0 + qcol;
    }

    float outa[4][8];
    #pragma unroll
    for (int r = 0; r < 4; ++r)
        #pragma unroll
        for (int db = 0; db < 8; ++db) outa[r][db] = 0.f;

#define KFRG(KT,RB) (const v4i*)(K8 + ((size_t)((KT)*128 + 32*w + 16*(RB) + n)*32 + bhi)*128 + 16*quad)

#define P2_QK_RB(MASKED, T0G, A0, A1, RB)                                        \
  do {                                                                           \
    int trow = 32*w + 16*(RB);                                                   \
    float ksr[4], kmr[4], skr[4];                                                \
    int tgb = (T0G) + trow + 4*quad;                                             \
    _Pragma("unroll")                                                            \
    for (int r = 0; r < 4; ++r) {                                                \
        int tl = trow + 4*quad + r;                                              \
        ksr[r] = ktA[tl]; kmr[r] = ktB[tl]; skr[r] = ktC[tl];                    \
    }                                                                            \
    _Pragma("unroll")                                                            \
    for (int cb = 0; cb < 4; ++cb) {                                             \
        v4i acc = MFMA16(A0, qb0[cb], vzero);                                    \
        acc = MFMA16(A1, qb1[cb], acc);                                          \
        int cby[4];                                                              \
        _Pragma("unroll")                                                        \
        for (int r = 0; r < 4; ++r) {                                            \
            float Sf = (float)acc[r];                                            \
            float x = fmaf(ksr[r], fmaf(qc1[cb], Sf, qc2[cb]*skr[r]),            \
                           fmaf(kmr[r], qc3[cb], qmxn[cb]));                     \
            if (MASKED) x = (tgb + r > qgq[cb]) ? -INFINITY : x;                 \
            float e = EXP2F(x);                                                  \
            float f = fmaf(e, qu1[cb], qw1[cb]) + 8388608.0f; /* RNE int */      \
            cby[r] = __float_as_int(f);                                          \
        }                                                                        \
        unsigned t01 = __builtin_amdgcn_perm((unsigned)cby[1],                   \
                                             (unsigned)cby[0], 0x00000400u);     \
        unsigned t23 = __builtin_amdgcn_perm((unsigned)cby[3],                   \
                                             (unsigned)cby[2], 0x04000000u);     \
        int packed = (int)(__builtin_amdgcn_perm(t23, t01, 0x07060100u)          \
                           ^ 0x80808080u);  /* code - 128 per byte */            \
        *(int*)(pcs + (16*cb + n)*144 + trow + 4*quad) = packed;                 \
    }                                                                            \
  } while (0)

#define P2_PV()                                                                  \
  do {                                                                           \
    v4i a0 = *(const v4i*)(pcs + (16*w + n)*144 + 16*quad);                      \
    v4i a1 = *(const v4i*)(pcs + (16*w + n)*144 + 64 + 16*quad);                 \
    v4i c1a = MFMA16(a0, ones, vzero);                                           \
    c1a = MFMA16(a1, ones, c1a);                                                 \
    float c1f[4];                                                                \
    _Pragma("unroll")                                                            \
    for (int r = 0; r < 4; ++r) c1f[r] = (float)c1a[r];                          \
    _Pragma("unroll")                                                            \
    for (int db = 0; db < 8; ++db) {                                             \
        v4i b0 = *(const v4i*)(kv8s + (16*db + n)*144 + 16*quad);                \
        v4i b1 = *(const v4i*)(kv8s + (16*db + n)*144 + 64 + 16*quad);           \
        v4i cv = MFMA16(a0, b0, vzero);                                          \
        cv = MFMA16(a1, b1, cv);                                                 \
        int d = 16*db + n;                                                       \
        float vs = vsA[d], vm = vsB[d];                                          \
        _Pragma("unroll")                                                        \
        for (int r = 0; r < 4; ++r)                                              \
            outa[r][db] = fmaf(vs, (float)cv[r],                                 \
                               fmaf(vm, c1f[r], outa[r][db]));                   \
    }                                                                            \
  } while (0)

    // ================= Phase 2 (register-prefetched staging) =================
    {
        uint4 pv0 = *VSTG(0,0), pv1 = *VSTG(0,1), pv2 = *VSTG(0,2), pv3 = *VSTG(0,3);
        v4i ka00 = *KFRG(0,0), ka01 = *(KFRG(0,0) + 4);
        v4i ka10 = *KFRG(0,1), ka11 = *(KFRG(0,1) + 4);
        int si0 = tc*32 + bhi;
        float nA = KSC[si0], nB = KMN[si0], nC = SKs[si0];
        int vi0 = (b*NH + h)*HD + tc;
        float vA = VSC[vi0], vB = VMN[vi0];
        for (int kt = 0; ; ++kt) {
            const int t0g = kt * 128;
            __syncthreads();                 // prior PV reads of kv8s/pcs done
            *(uint4*)(kv8s + (trb+ 0)*144 + tdo) = pv0;
            *(uint4*)(kv8s + (trb+32)*144 + tdo) = pv1;
            *(uint4*)(kv8s + (trb+64)*144 + tdo) = pv2;
            *(uint4*)(kv8s + (trb+96)*144 + tdo) = pv3;
            if (tid < 128) { ktA[tid] = nA*SCALE2; ktB[tid] = nB*SCALE2; ktC[tid] = nC; }
            else           { vsA[tc] = vA; vsB[tc] = vB; }
            __syncthreads();
            const int kn = (kt < kt_end) ? kt + 1 : kt_end;   // clamped next
            pv0 = *VSTG(kn,0); pv1 = *VSTG(kn,1); pv2 = *VSTG(kn,2); pv3 = *VSTG(kn,3);
            { int si = (kn*128 + tc)*32 + bhi; nA = KSC[si]; nB = KMN[si]; nC = SKs[si]; }
            { int vi = ((kn*BATCH + b)*NH + h)*HD + tc; vA = VSC[vi]; vB = VMN[vi]; }
            if (causal && kt == kt_end) {
                P2_QK_RB(true, t0g, ka00, ka01, 0);
                P2_QK_RB(true, t0g, ka10, ka11, 1);
            } else {
                P2_QK_RB(false, t0g, ka00, ka01, 0);
                P2_QK_RB(false, t0g, ka10, ka11, 1);
            }
            // reload K-fragments for next tile (after use; PV covers latency)
            ka00 = *KFRG(kn,0); ka01 = *(KFRG(kn,0) + 4);
            ka10 = *KFRG(kn,1); ka11 = *(KFRG(kn,1) + 4);
            __syncthreads();                 // pcs writes visible
            P2_PV();
            if (kt == kt_end) break;
        }
    }

    // ---- epilogue: out = psc*(outa + cgs) + pmin*vsum ----
    float pscr[4], pmnr[4];
    #pragma unroll
    for (int r = 0; r < 4; ++r) {
        int qq = 16*w + 4*quad + r;
        pscr[r] = rs_psc[qq]; pmnr[r] = rs_pmn[qq];
    }
    #pragma unroll
    for (int db = 0; db < 8; ++db) {
        int d = 16*db + n;
        float vsum = vsumL[d];
        float cgs  = cgsL[d];
        #pragma unroll
        for (int r = 0; r < 4; ++r) {
            int s = s0 + 16*w + 4*quad + r;
            OUT[(size_t)s*RSTR + boff + d] = fmaf(pscr[r], outa[r][db] + cgs, pmnr[r]*vsum);
        }
    }
}

extern "C" void kernel_launch(void* const* d_in, const int* in_sizes, int n_in,
                              void* d_out, int out_size, void* d_ws, size_t ws_size,
                              hipStream_t stream) {
    (void)in_sizes; (void)n_in; (void)out_size; (void)ws_size;
    const float* Q   = (const float*)d_in[0];
    const float* K   = (const float*)d_in[1];
    const float* V   = (const float*)d_in[2];
    const float* QMN = (const float*)d_in[3];
    const float* QSC = (const float*)d_in[4];
    const float* KMN = (const float*)d_in[5];
    const float* KSC = (const float*)d_in[6];
    const float* VMN = (const float*)d_in[7];
    const float* VSC = (const float*)d_in[8];
    const int*   CS  = (const int*)d_in[9];
    float* out = (float*)d_out;

    char* ws = (char*)d_ws;
    signed char* K8  = (signed char*)(ws + WS_K8);
    signed char* V8T = (signed char*)(ws + WS_V8T);
    float* SQs  = (float*)(ws + WS_SQ);
    float* SKs  = (float*)(ws + WS_SK);
    float* GSVp = (float*)(ws + WS_GSV);

    prep_pack<<<16384 + 512, 256, 0, stream>>>(Q, K, V, K8, SQs, SKs, V8T, GSVp);
    attn_main<<<1024, 256, 0, stream>>>(Q, K8, V8T, QMN, QSC, KMN, KSC, VMN, VSC,
                                        SQs, SKs, GSVp, CS, out);
}